// Round 1
// baseline (296.786 us; speedup 1.0000x reference)
//
#include <hip/hip_runtime.h>
#include <stdint.h>

#define EMBED 1024
#define NH 16
#define HD 64
#define SEQ 2048
#define BATCH 4
#define M_TOT (BATCH*SEQ)   // 8192
#define QSCALE 0.18033688011112042f   // log2(e)/sqrt(HD)

typedef __attribute__((ext_vector_type(8))) short short8;
typedef __attribute__((ext_vector_type(4))) float floatx4;
typedef __attribute__((ext_vector_type(4))) unsigned int uintx4;

__device__ __forceinline__ unsigned short f2bf(float f) {
    union { float f; unsigned int u; } v; v.f = f;
    unsigned int r = v.u + 0x7fffu + ((v.u >> 16) & 1u);
    return (unsigned short)(r >> 16);
}

__device__ __forceinline__ void load_lds16(const unsigned short* g, unsigned short* l) {
    __builtin_amdgcn_global_load_lds(
        (const __attribute__((address_space(1))) unsigned int*)g,
        (__attribute__((address_space(3))) unsigned int*)l, 16, 0, 0);
}

// ---- kernel 1: x fp32 -> bf16 ----
__global__ void cvt_x(const float* __restrict__ x, unsigned short* __restrict__ xb) {
    int i = (blockIdx.x * 256 + threadIdx.x) * 4;
    float4 v = *(const float4*)(x + i);
    ushort4 o;
    o.x = f2bf(v.x); o.y = f2bf(v.y); o.z = f2bf(v.z); o.w = f2bf(v.w);
    *(ushort4*)(xb + i) = o;
}

// ---- kernel 2: transpose W [k][n] fp32 -> WT [n][k] bf16 ----
__global__ void wtrans(const float* __restrict__ w0, const float* __restrict__ w1,
                       const float* __restrict__ w2, const float* __restrict__ w3,
                       unsigned short* __restrict__ t0, unsigned short* __restrict__ t1,
                       unsigned short* __restrict__ t2, unsigned short* __restrict__ t3) {
    __shared__ float tile[32][33];
    const float* W; unsigned short* T;
    switch (blockIdx.z) { case 0: W=w0; T=t0; break; case 1: W=w1; T=t1; break;
                          case 2: W=w2; T=t2; break; default: W=w3; T=t3; }
    int n0 = blockIdx.x * 32, k0 = blockIdx.y * 32;
    int tx = threadIdx.x, ty = threadIdx.y;
    #pragma unroll
    for (int i = 0; i < 4; i++)
        tile[ty + i*8][tx] = W[(k0 + ty + i*8) * EMBED + n0 + tx];
    __syncthreads();
    #pragma unroll
    for (int i = 0; i < 4; i++)
        T[(n0 + ty + i*8) * EMBED + k0 + tx] = f2bf(tile[tx][ty + i*8]);
}

// ---- kernel 3: 256x256 8-phase counted-vmcnt GEMM (T2+T3+T4+T5).
// C[M,N] = A[M,K] @ BT[N,K]^T + bias, K=1024 (NT=16 K-tiles of 64).
// 512 threads = 8 waves (2M x 4N), per-wave 128x64, acc[8][4] floatx4.
// LDS 128 KiB: lds[buf][A|B][256*64] bf16, double-buffered K-tiles.
// LDS swizzle: row r, 16B-chunk slot s holds logical chunk s ^ (r&7); achieved by
// pre-swizzling the per-lane GLOBAL source (global_load_lds dest is linear) and
// applying the same XOR on ds_read (rule: both-sides-or-neither).
// Phase schedule per K-tile t (buf = t&1):
//   P1: read A-lo(8)+B-lo(4); stage B-h0(t+1)->buf^1; bar; lgkm0; 16 MFMA Q(lo,lo); bar
//   P2: read B-hi(4);         stage B-h1(t+1)->buf^1; bar; lgkm0; 16 MFMA Q(lo,hi); bar
//   P3: read A-hi(8);                                  bar; lgkm0; 16 MFMA Q(hi,hi); bar
//   P4: stage A(t+2)->buf (safe: A reads of t done at P3's end-bar); 16 MFMA Q(hi,lo);
//       vmcnt(4)  <- t+1 fully landed, A(t+2)'s 4 loads stay in flight; bar
// Prologue issues A(0),B(0),A(1) then vmcnt(4). vmcnt reaches 0 only once (t=14).
// Grid 1D, id&7 = XCD; XCD owns a 4-mblock M-stripe (A-stripe 2MB, L2-resident);
// within XCD: mb inner (B-panel reused 4x), nb outer.
// mode 0: fused QKV, BT = WqT|WkT|WvT (3072x1024), which = nblk>>10:
//         0 -> Qb bf16 [B,H,S,D] * QSCALE; 1 -> Kb; 2 -> VTp [B,H,D,SEQ] tau-perm.
// mode 1: out-proj fp32 row-major [M,1024] + b0 -> o0.
#define ST_A(buf_, kt_) do { \
    const unsigned short* s_ = Asrc + (kt_)*64; \
    unsigned short* d_ = ldst + (buf_)*32768; \
    load_lds16(s_,              d_); \
    load_lds16(s_ + 64*EMBED,   d_ + 4096); \
    load_lds16(s_ + 128*EMBED,  d_ + 8192); \
    load_lds16(s_ + 192*EMBED,  d_ + 12288); \
  } while(0)
#define ST_B(buf_, kt_, h_) do { \
    const unsigned short* s_ = Bsrc + (kt_)*64 + (h_)*128*EMBED; \
    unsigned short* d_ = ldst + (buf_)*32768 + 16384 + (h_)*8192; \
    load_lds16(s_,              d_); \
    load_lds16(s_ + 64*EMBED,   d_ + 4096); \
  } while(0)

__global__ __launch_bounds__(512, 2) void gemm8(
        const unsigned short* __restrict__ A, const unsigned short* __restrict__ BT,
        const float* __restrict__ b0, const float* __restrict__ b1, const float* __restrict__ b2,
        void* __restrict__ o0, void* __restrict__ o1, void* __restrict__ o2, int mode) {
    __shared__ unsigned short lds[2][2][256*64];   // 128 KiB
    const int tid = threadIdx.x;
    const int lane = tid & 63, wave = tid >> 6;
    const int quad = lane >> 4, l16 = lane & 15;
    const int wm = wave >> 2, wn = wave & 3;       // wave tile 128x64 at (wm*128, wn*64)
    const int id = blockIdx.x;
    const int xcd = id & 7, j = id >> 3;
    const int mblk = (xcd * 4 + (j & 3)) * 256;
    const int nblk = (j >> 2) * 256;

    // staging: thread tid covers (row tid>>3, slot tid&7) of each 64-row issue;
    // slot s loads logical chunk s ^ (row&7)  (inverse-swizzled global source)
    const int srow = tid >> 3;
    const int scol = ((tid & 7) ^ (srow & 7)) * 8;
    const unsigned short* Asrc = A  + (size_t)(mblk + srow) * EMBED + scol;
    const unsigned short* Bsrc = BT + (size_t)(nblk + srow) * EMBED + scol;
    unsigned short* ldst = &lds[0][0][0] + wave * 512;   // HW scatters lane*16B

    // swizzled fragment-read chunk selects: logical chunk kk*4+quad at row ..+l16
    const int cs0 = ( quad      ^ (l16 & 7)) * 8;
    const int cs1 = ((quad ^ 4) ^ (l16 & 7)) * 8;
    const unsigned short* Abase = &lds[0][0][0] + (wm*128 + l16)*64;
    const unsigned short* Bbase = &lds[0][1][0] + (wn*64  + l16)*64;

    floatx4 acc[8][4];
    #pragma unroll
    for (int m=0;m<8;m++)
      #pragma unroll
      for (int n=0;n<4;n++) acc[m][n] = (floatx4){0.f,0.f,0.f,0.f};

    // prologue: tile0 (A+B), A of tile1; wait tile0 landed (A(1) stays in flight)
    ST_A(0,0); ST_B(0,0,0); ST_B(0,0,1);
    ST_A(1,1);
    asm volatile("s_waitcnt vmcnt(4)" ::: "memory");
    __builtin_amdgcn_s_barrier();

    #pragma unroll 2
    for (int t = 0; t < 16; ++t) {
        const int buf = t & 1;
        const unsigned short* Ab = Abase + buf*32768;
        const unsigned short* Bb = Bbase + buf*32768;
        short8 fA[4][2], fBlo[2][2], fBhi[2][2];
        // ---------- P1 ----------
        #pragma unroll
        for (int i=0;i<4;i++) {
            fA[i][0] = *(const short8*)(Ab + i*1024 + cs0);
            fA[i][1] = *(const short8*)(Ab + i*1024 + cs1);
        }
        #pragma unroll
        for (int n=0;n<2;n++) {
            fBlo[n][0] = *(const short8*)(Bb + n*1024 + cs0);
            fBlo[n][1] = *(const short8*)(Bb + n*1024 + cs1);
        }
        if (t < 15) ST_B(buf^1, t+1, 0);
        __builtin_amdgcn_s_barrier();
        asm volatile("s_waitcnt lgkmcnt(0)");
        __builtin_amdgcn_s_setprio(1);
        #pragma unroll
        for (int m=0;m<4;m++)
          #pragma unroll
          for (int n=0;n<2;n++) {
            acc[m][n] = __builtin_amdgcn_mfma_f32_16x16x32_bf16(fA[m][0], fBlo[n][0], acc[m][n], 0,0,0);
            acc[m][n] = __builtin_amdgcn_mfma_f32_16x16x32_bf16(fA[m][1], fBlo[n][1], acc[m][n], 0,0,0);
          }
        __builtin_amdgcn_s_setprio(0);
        __builtin_amdgcn_s_barrier();
        // ---------- P2 ----------
        #pragma unroll
        for (int n=0;n<2;n++) {
            fBhi[n][0] = *(const short8*)(Bb + (2+n)*1024 + cs0);
            fBhi[n][1] = *(const short8*)(Bb + (2+n)*1024 + cs1);
        }
        if (t < 15) ST_B(buf^1, t+1, 1);
        __builtin_amdgcn_s_barrier();
        asm volatile("s_waitcnt lgkmcnt(0)");
        __builtin_amdgcn_s_setprio(1);
        #pragma unroll
        for (int m=0;m<4;m++)
          #pragma unroll
          for (int n=0;n<2;n++) {
            acc[m][2+n] = __builtin_amdgcn_mfma_f32_16x16x32_bf16(fA[m][0], fBhi[n][0], acc[m][2+n], 0,0,0);
            acc[m][2+n] = __builtin_amdgcn_mfma_f32_16x16x32_bf16(fA[m][1], fBhi[n][1], acc[m][2+n], 0,0,0);
          }
        __builtin_amdgcn_s_setprio(0);
        __builtin_amdgcn_s_barrier();
        // ---------- P3 ----------
        #pragma unroll
        for (int i=0;i<4;i++) {
            fA[i][0] = *(const short8*)(Ab + (4+i)*1024 + cs0);
            fA[i][1] = *(const short8*)(Ab + (4+i)*1024 + cs1);
        }
        __builtin_amdgcn_s_barrier();
        asm volatile("s_waitcnt lgkmcnt(0)");
        __builtin_amdgcn_s_setprio(1);
        #pragma unroll
        for (int m=0;m<4;m++)
          #pragma unroll
          for (int n=0;n<2;n++) {
            acc[4+m][2+n] = __builtin_amdgcn_mfma_f32_16x16x32_bf16(fA[m][0], fBhi[n][0], acc[4+m][2+n], 0,0,0);
            acc[4+m][2+n] = __builtin_amdgcn_mfma_f32_16x16x32_bf16(fA[m][1], fBhi[n][1], acc[4+m][2+n], 0,0,0);
          }
        __builtin_amdgcn_s_setprio(0);
        __builtin_amdgcn_s_barrier();
        // ---------- P4 ----------  (A reads of tile t all done at the barrier above)
        if (t < 14) ST_A(buf, t+2);
        __builtin_amdgcn_s_setprio(1);
        #pragma unroll
        for (int m=0;m<4;m++)
          #pragma unroll
          for (int n=0;n<2;n++) {
            acc[4+m][n] = __builtin_amdgcn_mfma_f32_16x16x32_bf16(fA[m][0], fBlo[n][0], acc[4+m][n], 0,0,0);
            acc[4+m][n] = __builtin_amdgcn_mfma_f32_16x16x32_bf16(fA[m][1], fBlo[n][1], acc[4+m][n], 0,0,0);
          }
        __builtin_amdgcn_s_setprio(0);
        if (t < 14)       { asm volatile("s_waitcnt vmcnt(4)" ::: "memory"); }
        else if (t == 14) { asm volatile("s_waitcnt vmcnt(0)" ::: "memory"); }
        __builtin_amdgcn_s_barrier();
    }

    // epilogue: C/D layout col=lane&15, row=quad*4+reg
    if (mode == 1) {
        float* O = (float*)o0;
        #pragma unroll
        for (int mt=0;mt<8;mt++)
          #pragma unroll
          for (int nt=0;nt<4;nt++) {
            int col = nblk + wn*64 + nt*16 + l16;
            float bv = b0[col];
            #pragma unroll
            for (int r=0;r<4;r++) {
                int row = mblk + wm*128 + mt*16 + quad*4 + r;
                O[(size_t)row * EMBED + col] = acc[mt][nt][r] + bv;
            }
          }
    } else {
        int which = nblk >> 10;
        const float* bs = (which==0) ? b0 : (which==1) ? b1 : b2;
        unsigned short* O = (unsigned short*)((which==0) ? o0 : (which==1) ? o1 : o2);
        #pragma unroll
        for (int mt=0;mt<8;mt++)
          #pragma unroll
          for (int nt=0;nt<4;nt++) {
            int coll = (nblk & 1023) + wn*64 + nt*16 + l16;
            float bv = bs[coll];
            int h = coll >> 6, d = coll & 63;
            #pragma unroll
            for (int r=0;r<4;r++) {
                int row = mblk + wm*128 + mt*16 + quad*4 + r;
                int b = row >> 11, s = row & 2047;
                float v = acc[mt][nt][r] + bv;
                if (which == 0) {
                    v *= QSCALE;
                    O[((size_t)(b*NH + h)*SEQ + s)*HD + d] = f2bf(v);
                } else if (which == 1) {
                    O[((size_t)(b*NH + h)*SEQ + s)*HD + d] = f2bf(v);
                } else {
                    // tau-perm within each 32-col block: position p holds actual t s.t.
                    // p = ((s>>2)&3)*8 + ((s>>4)&1)*4 + (s&3)
                    int sp = (s & ~31) | (((s >> 2) & 3) << 3) | (((s >> 4) & 1) << 2) | (s & 3);
                    O[((size_t)(b*NH + h)*HD + d)*SEQ + sp] = f2bf(v);
                }
            }
          }
    }
}

// ---- kernel 4: flash attention, LDS-staged K/V (shared by all 8 waves), register-only P.
// S^T = mfma(A=K, B=Q) -> P^T fragment in regs -> O^T = mfma(A=V^T, B=P^T).
// K tile (32t x 64d, 4KB) and V^T tile (64d x 32t tau-perm'd, 4KB) staged once per block
// per iteration via global_load_lds; bank-conflict-free via XOR swizzle applied to the
// per-lane GLOBAL source address (LDS dest of global_load_lds is fixed base+lane*16).
__global__ __launch_bounds__(512, 4) void attn(
    const unsigned short* __restrict__ Q, const unsigned short* __restrict__ K,
    const unsigned short* __restrict__ VTp, unsigned short* __restrict__ O) {
    __shared__ unsigned short kv[4096];   // K tile [0,2048) + V tile [2048,4096) ushorts
    int tid = threadIdx.x;
    int lane = tid & 63, wave = tid >> 6;   // 8 waves
    int quad = lane >> 4, l16 = lane & 15;
    // 512 blocks: id = bh_low*64 + qblk*8 + xcd
    int id = blockIdx.x;
    int bh = (id & 7) * 8 + (id >> 6);
    int qblk = (id >> 3) & 7;
    int b = bh >> 4, h = bh & 15;
    int q0 = qblk * 256 + wave * 32;
    const unsigned short* Qb = Q + (size_t)bh * SEQ * HD;
    const unsigned short* Kb = K + (size_t)bh * SEQ * HD;
    const unsigned short* Vb = VTp + (size_t)bh * HD * SEQ;
    // staging source (per-lane, swizzled); LDS dest base per wave
    int li = (wave & 3) * 64 + lane;            // 0..255 chunk index within K or V half
    const unsigned short* src;
    unsigned short* dst = kv + (wave & 3) * 512 + ((wave >> 2) ? 2048 : 0);
    int src_step;
    if (wave < 4) {
        int t = li >> 3, slot = li & 7;
        int dblk = slot ^ (t & 7);
        src = Kb + (size_t)t * HD + dblk * 8;
        src_step = 32 * HD;                      // t advances by 32
    } else {
        int d = li >> 2, slot = li & 3;
        int swz = (d & 3) ^ ((d >> 2) & 3);
        src = Vb + (size_t)d * SEQ + (slot ^ swz) * 8;
        src_step = 32;                           // t advances by 32
    }
    short8 qf[2][2];
    #pragma unroll
    for (int mt=0;mt<2;mt++) {
        const unsigned short* qp = Qb + (size_t)(q0 + mt*16 + l16) * HD + quad*8;
        qf[mt][0] = *(const short8*)(qp);
        qf[mt][1] = *(const short8*)(qp + 32);
    }
    floatx4 o_acc[2][4], l_acc[2];
    #pragma unroll
    for (int mt=0;mt<2;mt++) {
        l_acc[mt] = (floatx4){0.f,0.f,0.f,0.f};
        #pragma unroll
        for (int dt=0;dt<4;dt++) o_acc[mt][dt] = (floatx4){0.f,0.f,0.f,0.f};
    }
    short8 ones;
    #pragma unroll
    for (int jj=0;jj<8;jj++) ones[jj] = (short)0x3F80;   // bf16 1.0
    // precomputed swizzled LDS read offsets (ushort units)
    int koff[2][2], voff[4];
    #pragma unroll
    for (int nt=0;nt<2;nt++) {
        int t = nt*16 + l16;
        #pragma unroll
        for (int hh=0;hh<2;hh++)
            koff[nt][hh] = t*64 + ((hh*4 + quad) ^ (t & 7)) * 8;
    }
    #pragma unroll
    for (int dt=0;dt<4;dt++) {
        int d = dt*16 + l16;
        voff[dt] = 2048 + d*32 + ((quad ^ (d & 3) ^ ((d >> 2) & 3))) * 8;
    }

    for (int tb = 0; tb < SEQ; tb += 32) {
        load_lds16(src, dst);
        src += src_step;
        __syncthreads();
        short8 kf[2][2], vf[4];
        #pragma unroll
        for (int nt=0;nt<2;nt++) {
            kf[nt][0] = *(const short8*)(kv + koff[nt][0]);
            kf[nt][1] = *(const short8*)(kv + koff[nt][1]);
        }
        #pragma unroll
        for (int dt=0;dt<4;dt++)
            vf[dt] = *(const short8*)(kv + voff[dt]);
        // S^T[t][q]: A = K rows (m = t), B = Q rows (n = q)
        floatx4 sacc[2][2];
        #pragma unroll
        for (int nt=0;nt<2;nt++)
          #pragma unroll
          for (int mt=0;mt<2;mt++) {
            floatx4 s = (floatx4){0.f,0.f,0.f,0.f};
            s = __builtin_amdgcn_mfma_f32_16x16x32_bf16(kf[nt][0], qf[mt][0], s, 0, 0, 0);
            s = __builtin_amdgcn_mfma_f32_16x16x32_bf16(kf[nt][1], qf[mt][1], s, 0, 0, 0);
            sacc[nt][mt] = s;
          }
        // P^T fragment in registers: slot j = nt*4 + r (matched by VT tau-perm)
        short8 pf[2];
        #pragma unroll
        for (int mt=0;mt<2;mt++) {
            uintx4 pu;
            #pragma unroll
            for (int jp=0;jp<4;jp++) {
                int nt = jp >> 1, rp = (jp & 1) * 2;
                union { float f; unsigned int u; } e0, e1;
                e0.f = __builtin_amdgcn_exp2f(sacc[nt][mt][rp]);
                e1.f = __builtin_amdgcn_exp2f(sacc[nt][mt][rp+1]);
                pu[jp] = ((e1.u + 0x8000u) & 0xFFFF0000u) | ((e0.u + 0x8000u) >> 16);
            }
            pf[mt] = __builtin_bit_cast(short8, pu);
        }
        #pragma unroll
        for (int mt=0;mt<2;mt++) {
            l_acc[mt] = __builtin_amdgcn_mfma_f32_16x16x32_bf16(ones, pf[mt], l_acc[mt], 0, 0, 0);
            #pragma unroll
            for (int dt=0;dt<4;dt++)
                o_acc[mt][dt] = __builtin_amdgcn_mfma_f32_16x16x32_bf16(vf[dt], pf[mt], o_acc[mt][dt], 0, 0, 0);
        }
        __syncthreads();   // protect LDS before next stage
    }
    // epilogue: o_acc[mt][dt][r] = O^T[d = dt*16+quad*4+r][q = mt*16+l16]; l replicated
    #pragma unroll
    for (int mt=0;mt<2;mt++) {
        float inv = 1.f / l_acc[mt][0];
        int s = q0 + mt*16 + l16;
        #pragma unroll
        for (int dt=0;dt<4;dt++) {
            ushort4 w;
            w.x = f2bf(o_acc[mt][dt][0]*inv);
            w.y = f2bf(o_acc[mt][dt][1]*inv);
            w.z = f2bf(o_acc[mt][dt][2]*inv);
            w.w = f2bf(o_acc[mt][dt][3]*inv);
            *(ushort4*)(O + ((size_t)b*SEQ + s)*EMBED + h*HD + dt*16 + quad*4) = w;
        }
    }
}

extern "C" void kernel_launch(void* const* d_in, const int* in_sizes, int n_in,
                              void* d_out, int out_size, void* d_ws, size_t ws_size,
                              hipStream_t stream) {
    const float* x  = (const float*)d_in[0];
    const float* Wq = (const float*)d_in[1]; const float* bq = (const float*)d_in[2];
    const float* Wk = (const float*)d_in[3]; const float* bk = (const float*)d_in[4];
    const float* Wv = (const float*)d_in[5]; const float* bv = (const float*)d_in[6];
    const float* Wo = (const float*)d_in[7]; const float* bo = (const float*)d_in[8];
    char* ws = (char*)d_ws;
    unsigned short* xb  = (unsigned short*)(ws);                      // 16 MB, reused as O later
    unsigned short* WqT = (unsigned short*)(ws + (16ull<<20));        // 2 MB each; Wq|Wk|Wv contiguous
    unsigned short* WkT = (unsigned short*)(ws + (18ull<<20));
    unsigned short* WvT = (unsigned short*)(ws + (20ull<<20));
    unsigned short* WoT = (unsigned short*)(ws + (22ull<<20));
    unsigned short* Qb  = (unsigned short*)(ws + (24ull<<20));        // 16 MB
    unsigned short* Kb  = (unsigned short*)(ws + (40ull<<20));        // 16 MB
    unsigned short* VTb = (unsigned short*)(ws + (56ull<<20));        // 16 MB  (total 72 MB)
    unsigned short* Ob  = xb;   // xb dead after QKV GEMM; reuse for attention output

    cvt_x<<<(M_TOT*EMBED)/1024, 256, 0, stream>>>(x, xb);
    wtrans<<<dim3(32,32,4), dim3(32,8), 0, stream>>>(Wq,Wk,Wv,Wo, WqT,WkT,WvT,WoT);
    // fused QKV: BT = WqT|WkT|WvT (contiguous), N = 3072 -> 32x12 = 384 blocks
    gemm8<<<dim3(384), 512, 0, stream>>>(xb, WqT, bq, bk, bv, Qb, Kb, VTb, 0);
    attn<<<dim3(512), 512, 0, stream>>>(Qb, Kb, VTb, Ob);
    // out-proj: 32x4 = 128 blocks
    gemm8<<<dim3(128), 512, 0, stream>>>(Ob, WoT, bo, bo, bo, (float*)d_out, nullptr, nullptr, 1);
}

// Round 3
// 289.135 us; speedup vs baseline: 1.0265x; 1.0265x over previous
//
#include <hip/hip_runtime.h>
#include <stdint.h>

#define EMBED 1024
#define NH 16
#define HD 64
#define SEQ 2048
#define BATCH 4
#define M_TOT (BATCH*SEQ)   // 8192
#define QSCALE 0.18033688011112042f   // log2(e)/sqrt(HD)

typedef __attribute__((ext_vector_type(8))) short short8;
typedef __attribute__((ext_vector_type(4))) float floatx4;
typedef __attribute__((ext_vector_type(4))) unsigned int uintx4;

__device__ __forceinline__ unsigned short f2bf(float f) {
    union { float f; unsigned int u; } v; v.f = f;
    unsigned int r = v.u + 0x7fffu + ((v.u >> 16) & 1u);
    return (unsigned short)(r >> 16);
}

__device__ __forceinline__ void load_lds16(const unsigned short* g, unsigned short* l) {
    __builtin_amdgcn_global_load_lds(
        (const __attribute__((address_space(1))) unsigned int*)g,
        (__attribute__((address_space(3))) unsigned int*)l, 16, 0, 0);
}

// ---- kernel 1: x fp32 -> bf16 ----
__global__ void cvt_x(const float* __restrict__ x, unsigned short* __restrict__ xb) {
    int i = (blockIdx.x * 256 + threadIdx.x) * 4;
    float4 v = *(const float4*)(x + i);
    ushort4 o;
    o.x = f2bf(v.x); o.y = f2bf(v.y); o.z = f2bf(v.z); o.w = f2bf(v.w);
    *(ushort4*)(xb + i) = o;
}

// ---- kernel 2: transpose W [k][n] fp32 -> WT [n][k] bf16 ----
__global__ void wtrans(const float* __restrict__ w0, const float* __restrict__ w1,
                       const float* __restrict__ w2, const float* __restrict__ w3,
                       unsigned short* __restrict__ t0, unsigned short* __restrict__ t1,
                       unsigned short* __restrict__ t2, unsigned short* __restrict__ t3) {
    __shared__ float tile[32][33];
    const float* W; unsigned short* T;
    switch (blockIdx.z) { case 0: W=w0; T=t0; break; case 1: W=w1; T=t1; break;
                          case 2: W=w2; T=t2; break; default: W=w3; T=t3; }
    int n0 = blockIdx.x * 32, k0 = blockIdx.y * 32;
    int tx = threadIdx.x, ty = threadIdx.y;
    #pragma unroll
    for (int i = 0; i < 4; i++)
        tile[ty + i*8][tx] = W[(k0 + ty + i*8) * EMBED + n0 + tx];
    __syncthreads();
    #pragma unroll
    for (int i = 0; i < 4; i++)
        T[(n0 + ty + i*8) * EMBED + k0 + tx] = f2bf(tile[tx][ty + i*8]);
}

// ---- kernel 3: 256x256 8-phase GEMM, deep pipeline (m201 structure).
// C[M,N] = A[M,K] @ BT[N,K]^T + bias, K=1024 (16 K-tiles of BK=64).
// 512 threads = 8 waves (2M x 4N), per-wave 128x64, acc[8][4].
// LDS 128 KiB: [buf][A 16K ushorts | B 16K ushorts]; LDS row = global tile row;
// row r, 16B slot s holds logical chunk s^(r&7) (inverse-swizzled global source,
// same XOR on ds_read -- both-sides rule).
// STAGING HALVES ALIGNED TO FRAGMENT-READ GROUPS (round-2 race fix):
//   A-half h = rows with (row&64)==h*64  ({0-63,128-191} / {64-127,192-255})
//     = exactly the rows read by the m-lo (P1) / m-hi (P3) fragments.
//   B-half h = rows with (row&32)==h*32
//     = exactly the rows read by the n-lo (P1) / n-hi (P2) fragments.
// Pipeline (during tile t, buf=t&1): one half-tile staged per phase, 1.5 tiles
// ahead; ONE vmcnt(6) per K-tile at P4 completes exactly tile t+1, leaves
// t+2's three staged halves in flight:
//   P1: read A-lo(12)+B-lo; stage B-h1(t+1)->buf^1  [B-h1(t-1) read @P2(t-1)]
//   P2: read B-hi(4);       stage A-h0(t+2)->buf    [A-h0(t)  read @P1(t)]
//   P3: read A-hi(8);       stage B-h0(t+2)->buf    [B-h0(t)  read @P1/P2(t)]
//   P4: no reads;           stage A-h1(t+2)->buf    [A-h1(t)  read @P3(t)]; vmcnt(6)
// Each phase: {reads; stage; [lgkmcnt(8) if 12 reads]; bar; lgkmcnt(0);
// setprio(1); 16 MFMA; setprio(0); bar}.
// Grid: id&7 = XCD stripe (A-stripe L2-resident). mode 0 = fused QKV (N=3072),
// mode 1 = out-proj (fp32 out + bias).
#define ST_AH(buf_, kt_, h_) do { \
    const unsigned short* s_ = Asrc + (kt_)*64 + (h_)*64*EMBED; \
    unsigned short* d_ = ldst + (buf_)*32768 + (h_)*4096; \
    load_lds16(s_,              d_); \
    load_lds16(s_ + 128*EMBED,  d_ + 8192); \
  } while(0)
#define ST_BH(buf_, kt_, h_) do { \
    const unsigned short* s_ = Bsrc + (kt_)*64 + (h_)*32*EMBED; \
    unsigned short* d_ = bdst + (buf_)*32768 + (h_)*2048; \
    load_lds16(s_,              d_); \
    load_lds16(s_ + 128*EMBED,  d_ + 8192); \
  } while(0)

template<int MO, int NO>
__device__ __forceinline__ void mfma_quad(floatx4 (&acc)[8][4],
        const short8 (&a)[4][2], const short8 (&b)[2][2]) {
    #pragma unroll
    for (int k=0;k<2;k++)
      #pragma unroll
      for (int m=0;m<4;m++)
        #pragma unroll
        for (int n=0;n<2;n++)
          acc[MO+m][NO+n] = __builtin_amdgcn_mfma_f32_16x16x32_bf16(a[m][k], b[n][k], acc[MO+m][NO+n], 0,0,0);
}

template<bool B1, bool T2, int WAITN>
__device__ __forceinline__ void ktile(int t, int buf,
        const unsigned short* Abase, const unsigned short* Bbase,
        const unsigned short* Asrc, const unsigned short* Bsrc,
        unsigned short* ldst, unsigned short* bdst,
        int cs0, int cs1, floatx4 (&acc)[8][4]) {
    const unsigned short* Ab = Abase + buf*32768;
    const unsigned short* Bb = Bbase + buf*32768;
    short8 fA[4][2], fBlo[2][2], fBhi[2][2];
    // ---- P1: quadrant (m-lo, n-lo); 12 reads; stage B-h1(t+1) -> buf^1
    #pragma unroll
    for (int i=0;i<4;i++) {
        fA[i][0] = *(const short8*)(Ab + i*1024 + cs0);
        fA[i][1] = *(const short8*)(Ab + i*1024 + cs1);
    }
    #pragma unroll
    for (int n=0;n<2;n++) {
        fBlo[n][0] = *(const short8*)(Bb + n*1024 + cs0);
        fBlo[n][1] = *(const short8*)(Bb + n*1024 + cs1);
    }
    if (B1) ST_BH(buf^1, t+1, 1);
    asm volatile("s_waitcnt lgkmcnt(8)");
    __builtin_amdgcn_s_barrier();
    asm volatile("s_waitcnt lgkmcnt(0)");
    __builtin_amdgcn_s_setprio(1);
    mfma_quad<0,0>(acc, fA, fBlo);
    __builtin_amdgcn_s_setprio(0);
    __builtin_amdgcn_s_barrier();
    // ---- P2: quadrant (m-lo, n-hi); 4 reads; stage A-h0(t+2) -> buf
    #pragma unroll
    for (int n=0;n<2;n++) {
        fBhi[n][0] = *(const short8*)(Bb + (2+n)*1024 + cs0);
        fBhi[n][1] = *(const short8*)(Bb + (2+n)*1024 + cs1);
    }
    if (T2) ST_AH(buf, t+2, 0);
    __builtin_amdgcn_s_barrier();
    asm volatile("s_waitcnt lgkmcnt(0)");
    __builtin_amdgcn_s_setprio(1);
    mfma_quad<0,2>(acc, fA, fBhi);
    __builtin_amdgcn_s_setprio(0);
    __builtin_amdgcn_s_barrier();
    // ---- P3: quadrant (m-hi, n-hi); 8 reads; stage B-h0(t+2) -> buf
    #pragma unroll
    for (int i=0;i<4;i++) {
        fA[i][0] = *(const short8*)(Ab + (4+i)*1024 + cs0);
        fA[i][1] = *(const short8*)(Ab + (4+i)*1024 + cs1);
    }
    if (T2) ST_BH(buf, t+2, 0);
    __builtin_amdgcn_s_barrier();
    asm volatile("s_waitcnt lgkmcnt(0)");
    __builtin_amdgcn_s_setprio(1);
    mfma_quad<4,2>(acc, fA, fBhi);
    __builtin_amdgcn_s_setprio(0);
    __builtin_amdgcn_s_barrier();
    // ---- P4: quadrant (m-hi, n-lo); 0 reads; stage A-h1(t+2) -> buf; counted wait
    if (T2) ST_AH(buf, t+2, 1);
    __builtin_amdgcn_s_setprio(1);
    mfma_quad<4,0>(acc, fA, fBlo);
    __builtin_amdgcn_s_setprio(0);
    if (WAITN == 6)      { asm volatile("s_waitcnt vmcnt(6)" ::: "memory"); }
    else if (WAITN == 0) { asm volatile("s_waitcnt vmcnt(0)" ::: "memory"); }
    __builtin_amdgcn_s_barrier();
}

__global__ __launch_bounds__(512, 2) void gemm8(
        const unsigned short* __restrict__ A, const unsigned short* __restrict__ BT,
        const float* __restrict__ b0, const float* __restrict__ b1, const float* __restrict__ b2,
        void* __restrict__ o0, void* __restrict__ o1, void* __restrict__ o2, int mode) {
    __shared__ unsigned short lds[2*32768];   // 128 KiB
    const int tid = threadIdx.x;
    const int lane = tid & 63, wave = tid >> 6;
    const int quad = lane >> 4, l16 = lane & 15;
    const int wm = wave >> 2, wn = wave & 3;       // wave tile 128x64 at (wm*128, wn*64)
    const int id = blockIdx.x;
    const int xcd = id & 7, j = id >> 3;
    const int mblk = (xcd * 4 + (j & 3)) * 256;
    const int nblk = (j >> 2) * 256;

    // staging: thread tid covers (row tid>>3 of each 64-row issue, slot tid&7);
    // slot s loads logical chunk s ^ (row&7)  (inverse-swizzled global source).
    // A rows: srow + h*64 (+128 for 2nd issue)  -> (row&64)==h*64 half.
    // B rows: brow + h*32 (+128), brow = (srow&31)+((srow>>5)<<6) -> (row&32)==h*32 half.
    // Row remaps preserve row&7, so the chunk swizzle stays consistent.
    const int srow = tid >> 3;
    const int scol = ((tid & 7) ^ (srow & 7)) * 8;
    const int brow = (srow & 31) + ((srow >> 5) << 6);
    const unsigned short* Asrc = A  + (size_t)(mblk + srow) * EMBED + scol;
    const unsigned short* Bsrc = BT + (size_t)(nblk + brow) * EMBED + scol;
    unsigned short* ldst = lds + wave * 512;                               // A dest
    unsigned short* bdst = lds + 16384 + (wave & 3)*512 + (wave >> 2)*4096; // B dest

    // swizzled fragment-read chunk selects
    const int cs0 = ( quad      ^ (l16 & 7)) * 8;
    const int cs1 = ((quad ^ 4) ^ (l16 & 7)) * 8;
    const unsigned short* Abase = lds + (wm*128 + l16)*64;
    const unsigned short* Bbase = lds + 16384 + (wn*64 + l16)*64;

    floatx4 acc[8][4];
    #pragma unroll
    for (int m=0;m<8;m++)
      #pragma unroll
      for (int n=0;n<4;n++) acc[m][n] = (floatx4){0.f,0.f,0.f,0.f};

    // prologue: tile0 all 4 halves; then A-h0,B-h0,A-h1 of tile1; vmcnt(6)
    // (B-h1(1) is staged at P1(0)); tile0 fully resident after the wait.
    ST_AH(0,0,0); ST_BH(0,0,0); ST_BH(0,0,1); ST_AH(0,0,1);
    asm volatile("s_waitcnt vmcnt(4)" ::: "memory");
    ST_AH(1,1,0); ST_BH(1,1,0); ST_AH(1,1,1);
    asm volatile("s_waitcnt vmcnt(6)" ::: "memory");
    __builtin_amdgcn_s_barrier();

    #pragma unroll 2
    for (int t = 0; t < 14; ++t)
        ktile<true, true, 6>(t, t & 1, Abase, Bbase, Asrc, Bsrc, ldst, bdst, cs0, cs1, acc);
    ktile<true,  false, 0>(14, 0, Abase, Bbase, Asrc, Bsrc, ldst, bdst, cs0, cs1, acc);
    ktile<false, false, -1>(15, 1, Abase, Bbase, Asrc, Bsrc, ldst, bdst, cs0, cs1, acc);

    // epilogue: C/D layout col=lane&15, row=quad*4+reg
    if (mode == 1) {
        float* O = (float*)o0;
        #pragma unroll
        for (int mt=0;mt<8;mt++)
          #pragma unroll
          for (int nt=0;nt<4;nt++) {
            int col = nblk + wn*64 + nt*16 + l16;
            float bv = b0[col];
            #pragma unroll
            for (int r=0;r<4;r++) {
                int row = mblk + wm*128 + mt*16 + quad*4 + r;
                O[(size_t)row * EMBED + col] = acc[mt][nt][r] + bv;
            }
          }
    } else {
        int which = nblk >> 10;
        const float* bs = (which==0) ? b0 : (which==1) ? b1 : b2;
        unsigned short* O = (unsigned short*)((which==0) ? o0 : (which==1) ? o1 : o2);
        #pragma unroll
        for (int mt=0;mt<8;mt++)
          #pragma unroll
          for (int nt=0;nt<4;nt++) {
            int coll = (nblk & 1023) + wn*64 + nt*16 + l16;
            float bv = bs[coll];
            int h = coll >> 6, d = coll & 63;
            #pragma unroll
            for (int r=0;r<4;r++) {
                int row = mblk + wm*128 + mt*16 + quad*4 + r;
                int b = row >> 11, s = row & 2047;
                float v = acc[mt][nt][r] + bv;
                if (which == 0) {
                    v *= QSCALE;
                    O[((size_t)(b*NH + h)*SEQ + s)*HD + d] = f2bf(v);
                } else if (which == 1) {
                    O[((size_t)(b*NH + h)*SEQ + s)*HD + d] = f2bf(v);
                } else {
                    // tau-perm within each 32-col block: position p holds actual t s.t.
                    // p = ((s>>2)&3)*8 + ((s>>4)&1)*4 + (s&3)
                    int sp = (s & ~31) | (((s >> 2) & 3) << 3) | (((s >> 4) & 1) << 2) | (s & 3);
                    O[((size_t)(b*NH + h)*HD + d)*SEQ + sp] = f2bf(v);
                }
            }
          }
    }
}

// ---- kernel 4: flash attention, double-buffered LDS K/V staging with counted
// vmcnt (stage t+1 issued before computing t; vmcnt(1) leaves next stage in
// flight; raw s_barrier, never vmcnt(0) mid-loop). Register-only P.
// S^T = mfma(A=K, B=Q) -> P^T in regs -> O^T = mfma(A=V^T, B=P^T).
__global__ __launch_bounds__(512, 4) void attn(
    const unsigned short* __restrict__ Q, const unsigned short* __restrict__ K,
    const unsigned short* __restrict__ VTp, unsigned short* __restrict__ O) {
    __shared__ unsigned short kv[2][4096];   // per buf: K tile [0,2048) + V tile [2048,4096)
    unsigned short* kvf = &kv[0][0];
    int tid = threadIdx.x;
    int lane = tid & 63, wave = tid >> 6;   // 8 waves
    int quad = lane >> 4, l16 = lane & 15;
    // 512 blocks: id = bh_low*64 + qblk*8 + xcd
    int id = blockIdx.x;
    int bh = (id & 7) * 8 + (id >> 6);
    int qblk = (id >> 3) & 7;
    int b = bh >> 4, h = bh & 15;
    int q0 = qblk * 256 + wave * 32;
    const unsigned short* Qb = Q + (size_t)bh * SEQ * HD;
    const unsigned short* Kb = K + (size_t)bh * SEQ * HD;
    const unsigned short* Vb = VTp + (size_t)bh * HD * SEQ;
    // staging source (per-lane, swizzled); LDS dest offset per wave
    int li = (wave & 3) * 64 + lane;            // 0..255 chunk index within K or V half
    const unsigned short* src;
    int dstofs = (wave & 3) * 512 + ((wave >> 2) ? 2048 : 0);
    int src_step;
    if (wave < 4) {
        int t = li >> 3, slot = li & 7;
        int dblk = slot ^ (t & 7);
        src = Kb + (size_t)t * HD + dblk * 8;
        src_step = 32 * HD;                      // t advances by 32
    } else {
        int d = li >> 2, slot = li & 3;
        int swz = (d & 3) ^ ((d >> 2) & 3);
        src = Vb + (size_t)d * SEQ + (slot ^ swz) * 8;
        src_step = 32;                           // t advances by 32
    }
    short8 qf[2][2];
    #pragma unroll
    for (int mt=0;mt<2;mt++) {
        const unsigned short* qp = Qb + (size_t)(q0 + mt*16 + l16) * HD + quad*8;
        qf[mt][0] = *(const short8*)(qp);
        qf[mt][1] = *(const short8*)(qp + 32);
    }
    floatx4 o_acc[2][4], l_acc[2];
    #pragma unroll
    for (int mt=0;mt<2;mt++) {
        l_acc[mt] = (floatx4){0.f,0.f,0.f,0.f};
        #pragma unroll
        for (int dt=0;dt<4;dt++) o_acc[mt][dt] = (floatx4){0.f,0.f,0.f,0.f};
    }
    short8 ones;
    #pragma unroll
    for (int jj=0;jj<8;jj++) ones[jj] = (short)0x3F80;   // bf16 1.0
    // precomputed swizzled LDS read offsets (ushort units, relative to buf base)
    int koff[2][2], voff[4];
    #pragma unroll
    for (int nt=0;nt<2;nt++) {
        int t = nt*16 + l16;
        #pragma unroll
        for (int hh=0;hh<2;hh++)
            koff[nt][hh] = t*64 + ((hh*4 + quad) ^ (t & 7)) * 8;
    }
    #pragma unroll
    for (int dt=0;dt<4;dt++) {
        int d = dt*16 + l16;
        voff[dt] = 2048 + d*32 + ((quad ^ (d & 3) ^ ((d >> 2) & 3))) * 8;
    }

    // prologue: stage tile 0 into buf 0
    load_lds16(src, kvf + dstofs);
    src += src_step;

    for (int it = 0; it < 64; ++it) {
        const unsigned short* kb = kvf + (it & 1) * 4096;
        if (it < 63) {
            load_lds16(src, kvf + ((it & 1) ^ 1) * 4096 + dstofs);
            src += src_step;
            asm volatile("s_waitcnt vmcnt(1)" ::: "memory");
        } else {
            asm volatile("s_waitcnt vmcnt(0)" ::: "memory");
        }
        __builtin_amdgcn_s_barrier();
        asm volatile("" ::: "memory");
        short8 kf[2][2], vf[4];
        #pragma unroll
        for (int nt=0;nt<2;nt++) {
            kf[nt][0] = *(const short8*)(kb + koff[nt][0]);
            kf[nt][1] = *(const short8*)(kb + koff[nt][1]);
        }
        #pragma unroll
        for (int dt=0;dt<4;dt++)
            vf[dt] = *(const short8*)(kb + voff[dt]);
        // S^T[t][q]: A = K rows (m = t), B = Q rows (n = q)
        floatx4 sacc[2][2];
        __builtin_amdgcn_s_setprio(1);
        #pragma unroll
        for (int nt=0;nt<2;nt++)
          #pragma unroll
          for (int mt=0;mt<2;mt++) {
            floatx4 s = (floatx4){0.f,0.f,0.f,0.f};
            s = __builtin_amdgcn_mfma_f32_16x16x32_bf16(kf[nt][0], qf[mt][0], s, 0, 0, 0);
            s = __builtin_amdgcn_mfma_f32_16x16x32_bf16(kf[nt][1], qf[mt][1], s, 0, 0, 0);
            sacc[nt][mt] = s;
          }
        __builtin_amdgcn_s_setprio(0);
        // P^T fragment in registers: slot j = nt*4 + r (matched by VT tau-perm)
        short8 pf[2];
        #pragma unroll
        for (int mt=0;mt<2;mt++) {
            uintx4 pu;
            #pragma unroll
            for (int jp=0;jp<4;jp++) {
                int nt = jp >> 1, rp = (jp & 1) * 2;
                union { float f; unsigned int u; } e0, e1;
                e0.f = __builtin_amdgcn_exp2f(sacc[nt][mt][rp]);
                e1.f = __builtin_amdgcn_exp2f(sacc[nt][mt][rp+1]);
                pu[jp] = ((e1.u + 0x8000u) & 0xFFFF0000u) | ((e0.u + 0x8000u) >> 16);
            }
            pf[mt] = __builtin_bit_cast(short8, pu);
        }
        __builtin_amdgcn_s_setprio(1);
        #pragma unroll
        for (int mt=0;mt<2;mt++) {
            l_acc[mt] = __builtin_amdgcn_mfma_f32_16x16x32_bf16(ones, pf[mt], l_acc[mt], 0, 0, 0);
            #pragma unroll
            for (int dt=0;dt<4;dt++)
                o_acc[mt][dt] = __builtin_amdgcn_mfma_f32_16x16x32_bf16(vf[dt], pf[mt], o_acc[mt][dt], 0, 0, 0);
        }
        __builtin_amdgcn_s_setprio(0);
        asm volatile("" ::: "memory");
        __builtin_amdgcn_s_barrier();   // all reads of this buf done before next overwrite
    }
    // epilogue: o_acc[mt][dt][r] = O^T[d = dt*16+quad*4+r][q = mt*16+l16]; l replicated
    #pragma unroll
    for (int mt=0;mt<2;mt++) {
        float inv = 1.f / l_acc[mt][0];
        int s = q0 + mt*16 + l16;
        #pragma unroll
        for (int dt=0;dt<4;dt++) {
            ushort4 w;
            w.x = f2bf(o_acc[mt][dt][0]*inv);
            w.y = f2bf(o_acc[mt][dt][1]*inv);
            w.z = f2bf(o_acc[mt][dt][2]*inv);
            w.w = f2bf(o_acc[mt][dt][3]*inv);
            *(ushort4*)(O + ((size_t)b*SEQ + s)*EMBED + h*HD + dt*16 + quad*4) = w;
        }
    }
}

extern "C" void kernel_launch(void* const* d_in, const int* in_sizes, int n_in,
                              void* d_out, int out_size, void* d_ws, size_t ws_size,
                              hipStream_t stream) {
    const float* x  = (const float*)d_in[0];
    const float* Wq = (const float*)d_in[1]; const float* bq = (const float*)d_in[2];
    const float* Wk = (const float*)d_in[3]; const float* bk = (const float*)d_in[4];
    const float* Wv = (const float*)d_in[5]; const float* bv = (const float*)d_in[6];
    const float* Wo = (const float*)d_in[7]; const float* bo = (const float*)d_in[8];
    char* ws = (char*)d_ws;
    unsigned short* xb  = (unsigned short*)(ws);                      // 16 MB, reused as O later
    unsigned short* WqT = (unsigned short*)(ws + (16ull<<20));        // 2 MB each; Wq|Wk|Wv contiguous
    unsigned short* WkT = (unsigned short*)(ws + (18ull<<20));
    unsigned short* WvT = (unsigned short*)(ws + (20ull<<20));
    unsigned short* WoT = (unsigned short*)(ws + (22ull<<20));
    unsigned short* Qb  = (unsigned short*)(ws + (24ull<<20));        // 16 MB
    unsigned short* Kb  = (unsigned short*)(ws + (40ull<<20));        // 16 MB
    unsigned short* VTb = (unsigned short*)(ws + (56ull<<20));        // 16 MB  (total 72 MB)
    unsigned short* Ob  = xb;   // xb dead after QKV GEMM; reuse for attention output

    cvt_x<<<(M_TOT*EMBED)/1024, 256, 0, stream>>>(x, xb);
    wtrans<<<dim3(32,32,4), dim3(32,8), 0, stream>>>(Wq,Wk,Wv,Wo, WqT,WkT,WvT,WoT);
    // fused QKV: BT = WqT|WkT|WvT (contiguous), N = 3072 -> 32x12 = 384 blocks
    gemm8<<<dim3(384), 512, 0, stream>>>(xb, WqT, bq, bk, bv, Qb, Kb, VTb, 0);
    attn<<<dim3(512), 512, 0, stream>>>(Qb, Kb, VTb, Ob);
    // out-proj: 32x4 = 128 blocks
    gemm8<<<dim3(128), 512, 0, stream>>>(Ob, WoT, bo, bo, bo, (float*)d_out, nullptr, nullptr, 1);
}

// Round 4
// 267.726 us; speedup vs baseline: 1.1085x; 1.0800x over previous
//
#include <hip/hip_runtime.h>
#include <stdint.h>

#define EMBED 1024
#define NH 16
#define HD 64
#define SEQ 2048
#define BATCH 4
#define M_TOT (BATCH*SEQ)   // 8192
#define QSCALE 0.18033688011112042f   // log2(e)/sqrt(HD)

typedef __attribute__((ext_vector_type(8))) short short8;
typedef __attribute__((ext_vector_type(4))) float floatx4;
typedef __attribute__((ext_vector_type(4))) unsigned int uintx4;

__device__ __forceinline__ unsigned short f2bf(float f) {
    union { float f; unsigned int u; } v; v.f = f;
    unsigned int r = v.u + 0x7fffu + ((v.u >> 16) & 1u);
    return (unsigned short)(r >> 16);
}

__device__ __forceinline__ void load_lds16(const unsigned short* g, unsigned short* l) {
    __builtin_amdgcn_global_load_lds(
        (const __attribute__((address_space(1))) unsigned int*)g,
        (__attribute__((address_space(3))) unsigned int*)l, 16, 0, 0);
}

// ---- kernel 1: x fp32 -> bf16 ----
__global__ void cvt_x(const float* __restrict__ x, unsigned short* __restrict__ xb) {
    int i = (blockIdx.x * 256 + threadIdx.x) * 4;
    float4 v = *(const float4*)(x + i);
    ushort4 o;
    o.x = f2bf(v.x); o.y = f2bf(v.y); o.z = f2bf(v.z); o.w = f2bf(v.w);
    *(ushort4*)(xb + i) = o;
}

// ---- kernel 2: transpose W [k][n] fp32 -> WT [n][k] bf16 ----
__global__ void wtrans(const float* __restrict__ w0, const float* __restrict__ w1,
                       const float* __restrict__ w2, const float* __restrict__ w3,
                       unsigned short* __restrict__ t0, unsigned short* __restrict__ t1,
                       unsigned short* __restrict__ t2, unsigned short* __restrict__ t3) {
    __shared__ float tile[32][33];
    const float* W; unsigned short* T;
    switch (blockIdx.z) { case 0: W=w0; T=t0; break; case 1: W=w1; T=t1; break;
                          case 2: W=w2; T=t2; break; default: W=w3; T=t3; }
    int n0 = blockIdx.x * 32, k0 = blockIdx.y * 32;
    int tx = threadIdx.x, ty = threadIdx.y;
    #pragma unroll
    for (int i = 0; i < 4; i++)
        tile[ty + i*8][tx] = W[(k0 + ty + i*8) * EMBED + n0 + tx];
    __syncthreads();
    #pragma unroll
    for (int i = 0; i < 4; i++)
        T[(n0 + ty + i*8) * EMBED + k0 + tx] = f2bf(tile[tx][ty + i*8]);
}

// ---- kernel 3: 256x256 GEMM, BK=32, QUAD-buffered LDS, ONE barrier per K-tile.
// C[M,N] = A[M,K] @ BT[N,K]^T + bias, K=1024 (32 K-tiles of 32).
// 512 threads = 8 waves (2M x 4N), per-wave 128x64, acc[8][4] (one MFMA per acc per tile).
// LDS 128 KiB = 4 bufs x (A 16KB | B 16KB). Swizzle: row r (64B = 4 chunks of 16B),
// slot s holds logical chunk s^(r&3); inverse-swizzled global source (global_load_lds
// dest is linear), same XOR on ds_read. Wave's frag read: 4 quads x 16 rows ->
// 2 lanes/bank (free).
// Schedule per tile t: {12 ds_read_b128; stage tile t+3 -> buf (t+3)&3 (4 gloads);
// 32 MFMA (compiler interleaves with fine lgkmcnt); vmcnt(8); s_barrier}.
// Buffer safety: buf (t+3)&3 == buf (t-1)&3, last read in tile t-1; every wave's
// reads of t-1 complete before its MFMAs(t-1) (compiler waits) which precede its
// barrier arrival -> all reads done before any wave issues the stage in tile t.
// vmcnt(8) completes tile t+1 (leaves stages t+2,t+3 = 8 loads in flight); never
// drains to 0 until the tail. 32 barriers/block total (vs 128 in the 8-phase try).
// Grid: id&7 = XCD stripe (A-stripe 2MB, L2-resident).
// MODE 0: fused QKV (N=3072): which = nblk>>10: 0 -> Qb bf16 [B,H,S,D] * QSCALE;
//   1 -> Kb; 2 -> VTp bf16 [B,H,D,SEQ] tau-perm, written via LDS-transpose
//   (tau-perm + XOR swz on ds_write; readback + fully-coalesced dwordx4 stores).
// MODE 1: out-proj fp32 row-major [M,1024] + b0 -> o0.
#define ST32(kt_) do { \
    const int b_ = (kt_) & 3; \
    const unsigned short* sa_ = Asrc + (kt_)*32; \
    const unsigned short* sb_ = Bsrc + (kt_)*32; \
    unsigned short* da_ = ldstA + b_*16384; \
    unsigned short* db_ = ldstB + b_*16384; \
    load_lds16(sa_,             da_); \
    load_lds16(sa_ + 128*EMBED, da_ + 4096); \
    load_lds16(sb_,             db_); \
    load_lds16(sb_ + 128*EMBED, db_ + 4096); \
  } while(0)

template<int WAITN, bool STG>
__device__ __forceinline__ void kt32(int t,
        const unsigned short* Abase, const unsigned short* Bbase,
        const unsigned short* Asrc, const unsigned short* Bsrc,
        unsigned short* ldstA, unsigned short* ldstB, floatx4 (&acc)[8][4]) {
    const int bo = (t & 3) * 16384;
    short8 fA[8], fB[4];
    #pragma unroll
    for (int m=0;m<8;m++) fA[m] = *(const short8*)(Abase + bo + m*512);
    #pragma unroll
    for (int n=0;n<4;n++) fB[n] = *(const short8*)(Bbase + bo + n*512);
    if (STG) ST32(t+3);
    #pragma unroll
    for (int m=0;m<8;m++)
      #pragma unroll
      for (int n=0;n<4;n++)
        acc[m][n] = __builtin_amdgcn_mfma_f32_16x16x32_bf16(fA[m], fB[n], acc[m][n], 0,0,0);
    if (WAITN >= 0) {
        asm volatile("s_waitcnt vmcnt(%0)" :: "i"(WAITN >= 0 ? WAITN : 0) : "memory");
        asm volatile("s_barrier" ::: "memory");
    }
}

template<int MODE>
__global__ __launch_bounds__(512, 2) void gemm32(
        const unsigned short* __restrict__ A, const unsigned short* __restrict__ BT,
        const float* __restrict__ b0, const float* __restrict__ b1, const float* __restrict__ b2,
        void* __restrict__ o0, void* __restrict__ o1, void* __restrict__ o2) {
    __shared__ unsigned short lds[4*16384];   // 128 KiB: [buf][A 8192 | B 8192] ushorts
    const int tid = threadIdx.x;
    const int lane = tid & 63, wave = tid >> 6;
    const int quad = lane >> 4, l16 = lane & 15;
    const int wm = wave >> 2, wn = wave & 3;       // wave tile 128x64 at (wm*128, wn*64)
    const int id = blockIdx.x;
    const int xcd = id & 7, j = id >> 3;
    const int mblk = (xcd * 4 + (j & 3)) * 256;
    const int nblk = (j >> 2) * 256;

    // staging: thread tid covers (row tid>>2, slot tid&3); slot s loads logical
    // chunk s ^ (row&3) (inverse-swizzled source); lines cover rows 0-127 / 128-255.
    const int srow = tid >> 2;
    const int scol = ((tid & 3) ^ (srow & 3)) * 8;
    const unsigned short* Asrc = A  + (size_t)(mblk + srow) * EMBED + scol;
    const unsigned short* Bsrc = BT + (size_t)(nblk + srow) * EMBED + scol;
    unsigned short* ldstA = lds + wave * 512;          // wave w stages rows w*16..+15
    unsigned short* ldstB = lds + 8192 + wave * 512;

    // swizzled fragment-read base: row (..+l16), chunk quad at slot quad^(l16&3)
    const int cs = (quad ^ (l16 & 3)) * 8;
    const unsigned short* Abase = lds + (wm*128 + l16)*32 + cs;
    const unsigned short* Bbase = lds + 8192 + (wn*64 + l16)*32 + cs;

    floatx4 acc[8][4];
    #pragma unroll
    for (int m=0;m<8;m++)
      #pragma unroll
      for (int n=0;n<4;n++) acc[m][n] = (floatx4){0.f,0.f,0.f,0.f};

    // prologue: stage tiles 0,1,2; wait tile 0 (8 = tiles 1,2 stay in flight)
    ST32(0); ST32(1); ST32(2);
    asm volatile("s_waitcnt vmcnt(8)" ::: "memory");
    asm volatile("s_barrier" ::: "memory");

    #pragma unroll 4
    for (int t = 0; t < 28; ++t)
        kt32<8,true>(t, Abase, Bbase, Asrc, Bsrc, ldstA, ldstB, acc);
    kt32<8,true >(28, Abase, Bbase, Asrc, Bsrc, ldstA, ldstB, acc);
    kt32<4,false>(29, Abase, Bbase, Asrc, Bsrc, ldstA, ldstB, acc);
    kt32<0,false>(30, Abase, Bbase, Asrc, Bsrc, ldstA, ldstB, acc);
    kt32<-1,false>(31, Abase, Bbase, Asrc, Bsrc, ldstA, ldstB, acc);

    // epilogue: C/D layout col=lane&15, row=quad*4+reg
    if (MODE == 1) {
        float* O = (float*)o0;
        #pragma unroll
        for (int mt=0;mt<8;mt++)
          #pragma unroll
          for (int nt=0;nt<4;nt++) {
            int col = nblk + wn*64 + nt*16 + l16;
            float bv = b0[col];
            #pragma unroll
            for (int r=0;r<4;r++) {
                int row = mblk + wm*128 + mt*16 + quad*4 + r;
                O[(size_t)row * EMBED + col] = acc[mt][nt][r] + bv;
            }
          }
    } else {
        int which = nblk >> 10;
        const float* bs = (which==0) ? b0 : (which==1) ? b1 : b2;
        if (which < 2) {
            unsigned short* O = (unsigned short*)((which==0) ? o0 : o1);
            float sc = (which==0) ? QSCALE : 1.f;
            #pragma unroll
            for (int mt=0;mt<8;mt++)
              #pragma unroll
              for (int nt=0;nt<4;nt++) {
                int coll = (nblk & 1023) + wn*64 + nt*16 + l16;
                float bv = bs[coll];
                int h = coll >> 6, d = coll & 63;
                #pragma unroll
                for (int r=0;r<4;r++) {
                    int row = mblk + wm*128 + mt*16 + quad*4 + r;
                    int b = row >> 11, s = row & 2047;
                    O[((size_t)(b*NH + h)*SEQ + s)*HD + d] = f2bf((acc[mt][nt][r] + bv) * sc);
                }
              }
        } else {
            // V: LDS transpose, tau-perm applied on the ds_write side.
            // T[c][sp] ushort, stride 256, XOR-swizzle sp bits 3-4 by (c&3) to
            // spread write banks; readback reads contiguous (s0^sw)+0..7.
            unsigned short* T = lds;
            __syncthreads();     // all K-loop LDS reads complete before overwrite
            #pragma unroll
            for (int nt=0;nt<4;nt++) {
                int cloc = wn*64 + nt*16 + l16;
                float bv = bs[(nblk & 1023) + cloc];
                int sw = (cloc & 3) << 3;
                #pragma unroll
                for (int mt=0;mt<8;mt++) {
                    int row0 = wm*128 + mt*16 + quad*4;
                    int sp0 = (row0 & ~31) | (((row0 >> 2) & 3) << 3) | (((row0 >> 4) & 1) << 2);
                    ushort4 w;
                    w.x = f2bf(acc[mt][nt][0] + bv);
                    w.y = f2bf(acc[mt][nt][1] + bv);
                    w.z = f2bf(acc[mt][nt][2] + bv);
                    w.w = f2bf(acc[mt][nt][3] + bv);
                    *(ushort4*)(T + cloc*256 + (sp0 ^ sw)) = w;
                }
            }
            __syncthreads();
            unsigned short* OV = (unsigned short*)o2;
            int s0 = (lane & 31) * 8, dloc = lane >> 5;
            size_t rowbase = ((size_t)((mblk >> 11)*1024 + (nblk & 1023))) * SEQ + (mblk & 2047);
            #pragma unroll
            for (int i=0;i<16;i++) {
                int c = wave*32 + i*2 + dloc;
                int sw2 = (c & 3) << 3;
                short8 v = *(const short8*)(T + c*256 + (s0 ^ sw2));
                *(short8*)(OV + rowbase + (size_t)c * SEQ + s0) = v;
            }
        }
    }
}

// ---- kernel 4: flash attention, double-buffered LDS K/V staging with counted
// vmcnt (stage t+1 issued before computing t; vmcnt(1) leaves next stage in
// flight; raw s_barrier, never vmcnt(0) mid-loop). Register-only P.
// S^T = mfma(A=K, B=Q) -> P^T in regs -> O^T = mfma(A=V^T, B=P^T).
__global__ __launch_bounds__(512, 4) void attn(
    const unsigned short* __restrict__ Q, const unsigned short* __restrict__ K,
    const unsigned short* __restrict__ VTp, unsigned short* __restrict__ O) {
    __shared__ unsigned short kv[2][4096];   // per buf: K tile [0,2048) + V tile [2048,4096)
    unsigned short* kvf = &kv[0][0];
    int tid = threadIdx.x;
    int lane = tid & 63, wave = tid >> 6;   // 8 waves
    int quad = lane >> 4, l16 = lane & 15;
    // 512 blocks: id = bh_low*64 + qblk*8 + xcd
    int id = blockIdx.x;
    int bh = (id & 7) * 8 + (id >> 6);
    int qblk = (id >> 3) & 7;
    int b = bh >> 4, h = bh & 15;
    int q0 = qblk * 256 + wave * 32;
    const unsigned short* Qb = Q + (size_t)bh * SEQ * HD;
    const unsigned short* Kb = K + (size_t)bh * SEQ * HD;
    const unsigned short* Vb = VTp + (size_t)bh * HD * SEQ;
    // staging source (per-lane, swizzled); LDS dest offset per wave
    int li = (wave & 3) * 64 + lane;            // 0..255 chunk index within K or V half
    const unsigned short* src;
    int dstofs = (wave & 3) * 512 + ((wave >> 2) ? 2048 : 0);
    int src_step;
    if (wave < 4) {
        int t = li >> 3, slot = li & 7;
        int dblk = slot ^ (t & 7);
        src = Kb + (size_t)t * HD + dblk * 8;
        src_step = 32 * HD;                      // t advances by 32
    } else {
        int d = li >> 2, slot = li & 3;
        int swz = (d & 3) ^ ((d >> 2) & 3);
        src = Vb + (size_t)d * SEQ + (slot ^ swz) * 8;
        src_step = 32;                           // t advances by 32
    }
    short8 qf[2][2];
    #pragma unroll
    for (int mt=0;mt<2;mt++) {
        const unsigned short* qp = Qb + (size_t)(q0 + mt*16 + l16) * HD + quad*8;
        qf[mt][0] = *(const short8*)(qp);
        qf[mt][1] = *(const short8*)(qp + 32);
    }
    floatx4 o_acc[2][4], l_acc[2];
    #pragma unroll
    for (int mt=0;mt<2;mt++) {
        l_acc[mt] = (floatx4){0.f,0.f,0.f,0.f};
        #pragma unroll
        for (int dt=0;dt<4;dt++) o_acc[mt][dt] = (floatx4){0.f,0.f,0.f,0.f};
    }
    short8 ones;
    #pragma unroll
    for (int jj=0;jj<8;jj++) ones[jj] = (short)0x3F80;   // bf16 1.0
    // precomputed swizzled LDS read offsets (ushort units, relative to buf base)
    int koff[2][2], voff[4];
    #pragma unroll
    for (int nt=0;nt<2;nt++) {
        int t = nt*16 + l16;
        #pragma unroll
        for (int hh=0;hh<2;hh++)
            koff[nt][hh] = t*64 + ((hh*4 + quad) ^ (t & 7)) * 8;
    }
    #pragma unroll
    for (int dt=0;dt<4;dt++) {
        int d = dt*16 + l16;
        voff[dt] = 2048 + d*32 + ((quad ^ (d & 3) ^ ((d >> 2) & 3))) * 8;
    }

    // prologue: stage tile 0 into buf 0
    load_lds16(src, kvf + dstofs);
    src += src_step;

    for (int it = 0; it < 64; ++it) {
        const unsigned short* kb = kvf + (it & 1) * 4096;
        if (it < 63) {
            load_lds16(src, kvf + ((it & 1) ^ 1) * 4096 + dstofs);
            src += src_step;
            asm volatile("s_waitcnt vmcnt(1)" ::: "memory");
        } else {
            asm volatile("s_waitcnt vmcnt(0)" ::: "memory");
        }
        __builtin_amdgcn_s_barrier();
        asm volatile("" ::: "memory");
        short8 kf[2][2], vf[4];
        #pragma unroll
        for (int nt=0;nt<2;nt++) {
            kf[nt][0] = *(const short8*)(kb + koff[nt][0]);
            kf[nt][1] = *(const short8*)(kb + koff[nt][1]);
        }
        #pragma unroll
        for (int dt=0;dt<4;dt++)
            vf[dt] = *(const short8*)(kb + voff[dt]);
        // S^T[t][q]: A = K rows (m = t), B = Q rows (n = q)
        floatx4 sacc[2][2];
        __builtin_amdgcn_s_setprio(1);
        #pragma unroll
        for (int nt=0;nt<2;nt++)
          #pragma unroll
          for (int mt=0;mt<2;mt++) {
            floatx4 s = (floatx4){0.f,0.f,0.f,0.f};
            s = __builtin_amdgcn_mfma_f32_16x16x32_bf16(kf[nt][0], qf[mt][0], s, 0, 0, 0);
            s = __builtin_amdgcn_mfma_f32_16x16x32_bf16(kf[nt][1], qf[mt][1], s, 0, 0, 0);
            sacc[nt][mt] = s;
          }
        __builtin_amdgcn_s_setprio(0);
        // P^T fragment in registers: slot j = nt*4 + r (matched by VT tau-perm)
        short8 pf[2];
        #pragma unroll
        for (int mt=0;mt<2;mt++) {
            uintx4 pu;
            #pragma unroll
            for (int jp=0;jp<4;jp++) {
                int nt = jp >> 1, rp = (jp & 1) * 2;
                union { float f; unsigned int u; } e0, e1;
                e0.f = __builtin_amdgcn_exp2f(sacc[nt][mt][rp]);
                e1.f = __builtin_amdgcn_exp2f(sacc[nt][mt][rp+1]);
                pu[jp] = ((e1.u + 0x8000u) & 0xFFFF0000u) | ((e0.u + 0x8000u) >> 16);
            }
            pf[mt] = __builtin_bit_cast(short8, pu);
        }
        __builtin_amdgcn_s_setprio(1);
        #pragma unroll
        for (int mt=0;mt<2;mt++) {
            l_acc[mt] = __builtin_amdgcn_mfma_f32_16x16x32_bf16(ones, pf[mt], l_acc[mt], 0, 0, 0);
            #pragma unroll
            for (int dt=0;dt<4;dt++)
                o_acc[mt][dt] = __builtin_amdgcn_mfma_f32_16x16x32_bf16(vf[dt], pf[mt], o_acc[mt][dt], 0, 0, 0);
        }
        __builtin_amdgcn_s_setprio(0);
        asm volatile("" ::: "memory");
        __builtin_amdgcn_s_barrier();   // all reads of this buf done before next overwrite
    }
    // epilogue: o_acc[mt][dt][r] = O^T[d = dt*16+quad*4+r][q = mt*16+l16]; l replicated
    #pragma unroll
    for (int mt=0;mt<2;mt++) {
        float inv = 1.f / l_acc[mt][0];
        int s = q0 + mt*16 + l16;
        #pragma unroll
        for (int dt=0;dt<4;dt++) {
            ushort4 w;
            w.x = f2bf(o_acc[mt][dt][0]*inv);
            w.y = f2bf(o_acc[mt][dt][1]*inv);
            w.z = f2bf(o_acc[mt][dt][2]*inv);
            w.w = f2bf(o_acc[mt][dt][3]*inv);
            *(ushort4*)(O + ((size_t)b*SEQ + s)*EMBED + h*HD + dt*16 + quad*4) = w;
        }
    }
}

extern "C" void kernel_launch(void* const* d_in, const int* in_sizes, int n_in,
                              void* d_out, int out_size, void* d_ws, size_t ws_size,
                              hipStream_t stream) {
    const float* x  = (const float*)d_in[0];
    const float* Wq = (const float*)d_in[1]; const float* bq = (const float*)d_in[2];
    const float* Wk = (const float*)d_in[3]; const float* bk = (const float*)d_in[4];
    const float* Wv = (const float*)d_in[5]; const float* bv = (const float*)d_in[6];
    const float* Wo = (const float*)d_in[7]; const float* bo = (const float*)d_in[8];
    char* ws = (char*)d_ws;
    unsigned short* xb  = (unsigned short*)(ws);                      // 16 MB, reused as O later
    unsigned short* WqT = (unsigned short*)(ws + (16ull<<20));        // 2 MB each; Wq|Wk|Wv contiguous
    unsigned short* WkT = (unsigned short*)(ws + (18ull<<20));
    unsigned short* WvT = (unsigned short*)(ws + (20ull<<20));
    unsigned short* WoT = (unsigned short*)(ws + (22ull<<20));
    unsigned short* Qb  = (unsigned short*)(ws + (24ull<<20));        // 16 MB
    unsigned short* Kb  = (unsigned short*)(ws + (40ull<<20));        // 16 MB
    unsigned short* VTb = (unsigned short*)(ws + (56ull<<20));        // 16 MB  (total 72 MB)
    unsigned short* Ob  = xb;   // xb dead after QKV GEMM; reuse for attention output

    cvt_x<<<(M_TOT*EMBED)/1024, 256, 0, stream>>>(x, xb);
    wtrans<<<dim3(32,32,4), dim3(32,8), 0, stream>>>(Wq,Wk,Wv,Wo, WqT,WkT,WvT,WoT);
    // fused QKV: BT = WqT|WkT|WvT (contiguous), N = 3072 -> 32x12 = 384 blocks
    gemm32<0><<<dim3(384), 512, 0, stream>>>(xb, WqT, bq, bk, bv, Qb, Kb, VTb);
    attn<<<dim3(512), 512, 0, stream>>>(Qb, Kb, VTb, Ob);
    // out-proj: 32x4 = 128 blocks
    gemm32<1><<<dim3(128), 512, 0, stream>>>(Ob, WoT, bo, bo, bo, (float*)d_out, nullptr, nullptr);
}